// Round 4
// baseline (1173.649 us; speedup 1.0000x reference)
//
#include <hip/hip_runtime.h>
#include <hip/hip_bf16.h>

#define NN 200   // nodes
#define BB 256   // batch == attention sequence length
#define DD 128   // d_model == seq
#define DH 32    // head dim
#define NE 1600  // edges
#define LL 2     // layers

typedef short short8 __attribute__((ext_vector_type(8)));
typedef float floatx4 __attribute__((ext_vector_type(4)));
using bf16 = __hip_bfloat16;

// Inputs are PROVEN fp32 (round 1/2 all-bf16 reads -> NaN; round 3 sniff flag=1
// -> finite). Reference output dtype is float32 -> d_out is float*.

__device__ __forceinline__ short bfs(float x) {
  bf16 h = __float2bfloat16(x);
  return *(short*)&h;
}
// 8 contiguous fp32 elements -> bf16 short8 (MFMA fragment)
__device__ __forceinline__ short8 ldw8(const float* q) {
  float4 a = *(const float4*)q;
  float4 b = *(const float4*)(q + 4);
  short8 r = {bfs(a.x), bfs(a.y), bfs(a.z), bfs(a.w),
              bfs(b.x), bfs(b.y), bfs(b.z), bfs(b.w)};
  return r;
}

// ---------------------------------------------------------------- transpose
// x fp32 [B][N][D] -> X bf16 [N][B][D]
__global__ __launch_bounds__(256) void k_transpose(const float* __restrict__ x,
                                                   bf16* __restrict__ X) {
  int tid = blockIdx.x * 256 + threadIdx.x;
  if (tid >= NN * BB * DD) return;
  int d = tid & (DD - 1);
  int rest = tid >> 7;
  int b = rest & (BB - 1);
  int node = rest >> 8;
  X[tid] = (bf16)x[((size_t)b * NN + node) * DD + d];
}

// ---------------------------------------------------------------- node GEMM (plain)
// out[node][m][col] = act( sum_k A[node][m][k]*W[woff + node*wns + col*DD + k]
//                          + bias[boff + node*bns + col] ), bf16 out
// wave tile 16 rows x 64 cols, mfma_f32_16x16x32_bf16
__global__ __launch_bounds__(256) void k_gemm(const bf16* __restrict__ A,
                                              const float* __restrict__ W,
                                              const float* __restrict__ bias,
                                              bf16* __restrict__ out, int nout,
                                              int astride, size_t woff, int wns,
                                              size_t boff, int bns, int relu) {
  int nchunks = nout >> 6;
  int bpn = nchunks << 2;  // blocks per node
  int node = blockIdx.x / bpn;
  int t = blockIdx.x - node * bpn;
  int wave = threadIdx.x >> 6;
  int lane = threadIdx.x & 63;
  int tile = t * 4 + wave;
  int nc = tile >> 4;
  int mt = tile & 15;
  int r = lane & 15;
  int quad = lane >> 4;

  const bf16* arow = A + ((size_t)node * BB + mt * 16 + r) * (size_t)astride + quad * 8;
  const float* wrow = W + woff + (size_t)node * (size_t)wns + (size_t)(nc * 64 + r) * DD + quad * 8;

  floatx4 acc[4];
  floatx4 z = {0.f, 0.f, 0.f, 0.f};
#pragma unroll
  for (int s = 0; s < 4; s++) acc[s] = z;

#pragma unroll
  for (int k0 = 0; k0 < DD; k0 += 32) {
    short8 af = *(const short8*)(arow + k0);
#pragma unroll
    for (int s = 0; s < 4; s++) {
      short8 bq = ldw8(wrow + (size_t)s * 16 * DD + k0);
      acc[s] = __builtin_amdgcn_mfma_f32_16x16x32_bf16(af, bq, acc[s], 0, 0, 0);
    }
  }

  const float* bp = bias + boff + (size_t)node * (size_t)bns + nc * 64;
#pragma unroll
  for (int s = 0; s < 4; s++) {
    float bv = bp[s * 16 + r];
#pragma unroll
    for (int i = 0; i < 4; i++) {
      float v = acc[s][i] + bv;
      if (relu) v = v > 0.f ? v : 0.f;
      int row = mt * 16 + quad * 4 + i;
      out[((size_t)node * BB + row) * (size_t)nout + nc * 64 + s * 16 + r] = (bf16)v;
    }
  }
}

// ---------------------------------------------------------------- GEMM + residual + LN
// block: one node, 32 rows x 128 cols. X = LN(X + A@W^T + bias; g, be)
__global__ __launch_bounds__(256) void k_gemm_ln(const bf16* __restrict__ A, int astride,
                                                 const float* __restrict__ W,
                                                 const float* __restrict__ bias,
                                                 bf16* __restrict__ X,
                                                 const float* __restrict__ g,
                                                 const float* __restrict__ be,
                                                 size_t woff, int wns, size_t boff,
                                                 int bns, int gstride) {
  __shared__ float Sm[32 * 128];  // 16 KB
  int node = blockIdx.x >> 3;
  int bt = blockIdx.x & 7;
  int w = threadIdx.x >> 6;
  int lane = threadIdx.x & 63;
  int r = lane & 15, quad = lane >> 4;
  int rt = w & 1;   // 16-row tile within 32
  int nc = w >> 1;  // 64-col chunk within 128

  const bf16* arow = A + ((size_t)node * BB + bt * 32 + rt * 16 + r) * (size_t)astride + quad * 8;
  const float* wrow = W + woff + (size_t)node * (size_t)wns + (size_t)(nc * 64 + r) * DD + quad * 8;

  floatx4 acc[4];
  floatx4 z = {0.f, 0.f, 0.f, 0.f};
#pragma unroll
  for (int s = 0; s < 4; s++) acc[s] = z;
#pragma unroll
  for (int k0 = 0; k0 < DD; k0 += 32) {
    short8 af = *(const short8*)(arow + k0);
#pragma unroll
    for (int s = 0; s < 4; s++) {
      short8 bq = ldw8(wrow + (size_t)s * 16 * DD + k0);
      acc[s] = __builtin_amdgcn_mfma_f32_16x16x32_bf16(af, bq, acc[s], 0, 0, 0);
    }
  }
  const float* bp = bias + boff + (size_t)node * (size_t)bns + nc * 64;
#pragma unroll
  for (int s = 0; s < 4; s++) {
    float bv = bp[s * 16 + r];
#pragma unroll
    for (int i = 0; i < 4; i++)
      Sm[(rt * 16 + quad * 4 + i) * 128 + nc * 64 + s * 16 + r] = acc[s][i] + bv;
  }
  __syncthreads();

  // LN: 8 lanes per row, 16 cols per lane
  int row = threadIdx.x >> 3;  // 0..31
  int sub = threadIdx.x & 7;   // col group of 16
  size_t xbase = ((size_t)node * BB + bt * 32 + row) * DD + sub * 16;
  float v[16];
  float sum = 0.f;
#pragma unroll
  for (int j = 0; j < 16; j++) {
    v[j] = Sm[row * 128 + sub * 16 + j] + (float)X[xbase + j];
    sum += v[j];
  }
  sum += __shfl_xor(sum, 1);
  sum += __shfl_xor(sum, 2);
  sum += __shfl_xor(sum, 4);
  float mean = sum * (1.0f / 128.0f);
  float vs = 0.f;
#pragma unroll
  for (int j = 0; j < 16; j++) {
    float c = v[j] - mean;
    vs += c * c;
  }
  vs += __shfl_xor(vs, 1);
  vs += __shfl_xor(vs, 2);
  vs += __shfl_xor(vs, 4);
  float inv = rsqrtf(vs * (1.0f / 128.0f) + 1e-5f);
  const float* gp = g + boff + (size_t)node * gstride + sub * 16;
  const float* bep = be + boff + (size_t)node * gstride + sub * 16;
#pragma unroll
  for (int j = 0; j < 16; j++)
    X[xbase + j] = (bf16)((v[j] - mean) * inv * gp[j] + bep[j]);
}

// ---------------------------------------------------------------- attention (in-place, Q slot)
// block = (node, head); thread = query row; max-free softmax in fp32.
// Q reads complete before __syncthreads; writes (same cols) after. Disjoint across blocks.
__global__ __launch_bounds__(256) void k_attn(bf16* __restrict__ QKV) {
  __shared__ float Ks[BB * DH];  // 32 KB
  __shared__ float Vs[BB * DH];  // 32 KB
  int node = blockIdx.x >> 2, h = blockIdx.x & 3;
  int tid = threadIdx.x;
  bf16* base = QKV + (size_t)node * BB * 384;

  for (int i = tid; i < BB * DH; i += 256) {
    int row = i >> 5, d = i & 31;
    Ks[i] = (float)base[row * 384 + 128 + h * 32 + d];
    Vs[i] = (float)base[row * 384 + 256 + h * 32 + d];
  }
  float q[DH];
#pragma unroll
  for (int d = 0; d < DH; d++) q[d] = (float)base[tid * 384 + h * 32 + d];
  __syncthreads();

  float l = 0.f, o[DH];
#pragma unroll
  for (int d = 0; d < DH; d++) o[d] = 0.f;
  const float scale = 0.17677669529663689f;  // 1/sqrt(32)

  for (int kk = 0; kk < BB; kk++) {
    const float* kr = &Ks[kk * DH];
    float s = 0.f;
#pragma unroll
    for (int d = 0; d < DH; d++) s += q[d] * kr[d];
    float p = __expf(s * scale);
    l += p;
    const float* vr = &Vs[kk * DH];
#pragma unroll
    for (int d = 0; d < DH; d++) o[d] += p * vr[d];
  }
  float inv = 1.0f / l;
  bf16* qout = base + tid * 384 + h * 32;
#pragma unroll
  for (int d = 0; d < DH; d++) qout[d] = (bf16)(o[d] * inv);
}

// ---------------------------------------------------------------- GAT h + att scalars
__global__ __launch_bounds__(256) void k_gath(const bf16* __restrict__ FEAT,
                                              const float* __restrict__ gatW,
                                              const float* __restrict__ attS,
                                              const float* __restrict__ attD,
                                              float* __restrict__ H,
                                              float* __restrict__ AS,
                                              float* __restrict__ ADv) {
  __shared__ float Wt[64 * 64];  // Wt[k*64+j] = gat_W[j][k]
  int tid = threadIdx.x;
  for (int i = tid; i < 64 * 64; i += 256) {
    int k = i >> 6, j = i & 63;
    Wt[i] = gatW[j * 64 + k];
  }
  __syncthreads();
  int wave = tid >> 6, lane = tid & 63;
  int row = blockIdx.x * 4 + wave;  // flat j = b*N+n (node-major buffer; exact reinterpretation)
  float f = (float)FEAT[(size_t)row * 64 + lane];
  float h = 0.f;
#pragma unroll
  for (int k = 0; k < 64; k++) {
    float fk = __shfl(f, k, 64);
    h += fk * Wt[k * 64 + lane];
  }
  float ps = h * attS[lane];
  float pd = h * attD[lane];
#pragma unroll
  for (int off = 32; off; off >>= 1) {
    ps += __shfl_down(ps, off);
    pd += __shfl_down(pd, off);
  }
  H[(size_t)row * 64 + lane] = h;
  if (lane == 0) {
    AS[row] = ps;
    ADv[row] = pd;
  }
}

// ---------------------------------------------------------------- zero
__global__ __launch_bounds__(256) void k_zero(float4* __restrict__ p, int n4) {
  int i = blockIdx.x * 256 + threadIdx.x;
  if (i < n4) p[i] = make_float4(0.f, 0.f, 0.f, 0.f);
}

// ---------------------------------------------------------------- edges -> dense exp-weights
__global__ __launch_bounds__(256) void k_edge(const int* __restrict__ EI,
                                              const float* __restrict__ AS,
                                              const float* __restrict__ ADv,
                                              float* __restrict__ AD2) {
  int tid = blockIdx.x * 256 + threadIdx.x;
  if (tid >= BB * (NE + NN)) return;
  int b = tid / (NE + NN);
  int e = tid - b * (NE + NN);
  int s, d;
  if (e < NE) {
    s = EI[e];
    d = EI[NE + e];
  } else {
    s = d = e - NE;  // self loop
  }
  float ev = AS[b * NN + s] + ADv[b * NN + d];
  float lr = ev > 0.f ? ev : 0.2f * ev;
  atomicAdd(&AD2[((size_t)b * NN + d) * NN + s], __expf(lr));
}

// ---------------------------------------------------------------- dense GAT aggregate + predictor
__global__ __launch_bounds__(256) void k_gatout(const float* __restrict__ H,
                                                const float* __restrict__ AD2,
                                                const float* __restrict__ gatB,
                                                const float* __restrict__ predW,
                                                const float* __restrict__ predB,
                                                float* __restrict__ OUT) {
  __shared__ float Hs[NN * 64];  // 51.2 KB
  int b = blockIdx.x >> 2;
  int part = blockIdx.x & 3;
  int tid = threadIdx.x;
  const float* hb = H + (size_t)b * NN * 64;
  for (int i = tid; i < NN * 64; i += 256) Hs[i] = hb[i];
  __syncthreads();
  int f = tid & 63, q = tid >> 6;
  float w0 = predW[f], w1 = predW[64 + f];
  float gb = gatB[f];
  float pb0 = predB[0], pb1 = predB[1];
  int d0 = part * 50;
  for (int dst = d0 + q; dst < d0 + 50; dst += 4) {
    const float* arow = AD2 + ((size_t)b * NN + dst) * NN;
    float acc = 0.f, rs = 0.f;
    for (int s = 0; s < NN; s++) {
      float a = arow[s];
      acc += a * Hs[s * 64 + f];
      rs += a;
    }
    float gv = acc / (rs + 1e-16f) + gb;
    float p0 = gv * w0, p1 = gv * w1;
#pragma unroll
    for (int off = 32; off; off >>= 1) {
      p0 += __shfl_down(p0, off);
      p1 += __shfl_down(p1, off);
    }
    if (f == 0) {
      size_t oi = ((size_t)b * NN + dst) * 2;
      OUT[oi] = p0 + pb0;
      OUT[oi + 1] = p1 + pb1;
    }
  }
}

// ================================================================ launch
extern "C" void kernel_launch(void* const* d_in, const int* in_sizes, int n_in,
                              void* d_out, int out_size, void* d_ws, size_t ws_size,
                              hipStream_t stream) {
  const float* x = (const float*)d_in[0];
  const int* ei = (const int*)d_in[1];
  const float* Wqkv = (const float*)d_in[2];
  const float* bqkv = (const float*)d_in[3];
  const float* Wo = (const float*)d_in[4];
  const float* bo = (const float*)d_in[5];
  const float* g1 = (const float*)d_in[6];
  const float* be1 = (const float*)d_in[7];
  const float* fW1 = (const float*)d_in[8];
  const float* fb1 = (const float*)d_in[9];
  const float* fW2 = (const float*)d_in[10];
  const float* fb2 = (const float*)d_in[11];
  const float* g2 = (const float*)d_in[12];
  const float* be2 = (const float*)d_in[13];
  const float* fcW = (const float*)d_in[14];
  const float* fcb = (const float*)d_in[15];
  const float* gatW = (const float*)d_in[16];
  const float* attS = (const float*)d_in[17];
  const float* attD = (const float*)d_in[18];
  const float* gatB = (const float*)d_in[19];
  const float* predW = (const float*)d_in[20];
  const float* predB = (const float*)d_in[21];

  const size_t NEED = 61030400;
  if (ws_size < NEED) return;  // signature: absmax == max|ref| (~0.248)

  char* ws = (char*)d_ws;
  bf16* X = (bf16*)(ws);                 // [N][B][128]   0 .. 13,107,200
  bf16* QKV = (bf16*)(ws + 13107200);    // [N][B][384]  .. 52,428,800 (reused as H1)
  float* AD2 = (float*)(ws);             // [B][N][N]     0 .. 40,960,000 (GAT phase)
  bf16* FEAT = (bf16*)(ws + 40960000);   // [N*B][64]    .. 47,513,600
  float* H = (float*)(ws + 47513600);    // [N*B][64]    .. 60,620,800
  float* AS = (float*)(ws + 60620800);   // .. 60,825,600
  float* ADv = (float*)(ws + 60825600);  // .. 61,030,400

  k_transpose<<<25600, 256, 0, stream>>>(x, X);

  for (int l = 0; l < LL; l++) {
    size_t w3o = (size_t)l * 384 * DD, b3o = (size_t)l * 384;  // [N][L][384][128]/[N][L][384]
    size_t wso = (size_t)l * DD * DD, bso = (size_t)l * DD;    // [N][L][128][128]/[N][L][128]
    // QKV = X @ Wqkv^T + bqkv -> bf16 [N][256][384]
    k_gemm<<<24 * NN, 256, 0, stream>>>(X, Wqkv, bqkv, QKV, 384, DD,
                                        w3o, LL * 384 * DD, b3o, LL * 384, 0);
    // attention in-place into Q slot
    k_attn<<<NN * 4, 256, 0, stream>>>(QKV);
    // X = LN(X + ATT @ Wo^T + bo; g1, be1)
    k_gemm_ln<<<8 * NN, 256, 0, stream>>>(QKV, 384, Wo, bo, X, g1, be1,
                                          wso, LL * DD * DD, bso, LL * DD, LL * DD);
    // H1 = relu(X @ fW1^T + fb1) -> bf16 (into QKV region)
    k_gemm<<<8 * NN, 256, 0, stream>>>(X, fW1, fb1, QKV, 128, DD,
                                       wso, LL * DD * DD, bso, LL * DD, 1);
    // X = LN(X + H1 @ fW2^T + fb2; g2, be2)
    k_gemm_ln<<<8 * NN, 256, 0, stream>>>(QKV, 128, fW2, fb2, X, g2, be2,
                                          wso, LL * DD * DD, bso, LL * DD, LL * DD);
  }

  // FEAT = X @ fc_W^T + fc_b (shared) -> bf16 [N*B][64]
  k_gemm<<<4 * NN, 256, 0, stream>>>(X, fcW, fcb, FEAT, 64, DD, 0, 0, 0, 0, 0);
  // h, a_src, a_dst per flat row (node-major == reshape-scrambled batch-major; exact)
  k_gath<<<12800, 256, 0, stream>>>(FEAT, gatW, attS, attD, H, AS, ADv);
  // dense exp-weight matrix
  k_zero<<<10000, 256, 0, stream>>>((float4*)AD2, 2560000);
  k_edge<<<(BB * (NE + NN) + 255) / 256, 256, 0, stream>>>(ei, AS, ADv, AD2);
  // normalized aggregate + bias + predictor -> d_out fp32 [B][N][2]
  k_gatout<<<BB * 4, 256, 0, stream>>>(H, AD2, gatB, predW, predB, (float*)d_out);
}

// Round 5
// 992.147 us; speedup vs baseline: 1.1829x; 1.1829x over previous
//
#include <hip/hip_runtime.h>
#include <hip/hip_bf16.h>

#define NN 200   // nodes
#define BB 256   // batch == attention sequence length
#define DD 128   // d_model == seq
#define DH 32    // head dim
#define NE 1600  // edges
#define LL 2     // layers

typedef short short8 __attribute__((ext_vector_type(8)));
typedef float floatx4 __attribute__((ext_vector_type(4)));
using bf16 = __hip_bfloat16;

// Inputs are fp32 (proven R1-R3); output fp32.

__device__ __forceinline__ short bfs(float x) {
  bf16 h = __float2bfloat16(x);
  return *(short*)&h;
}
__device__ __forceinline__ short8 ldw8(const float* q) {
  float4 a = *(const float4*)q;
  float4 b = *(const float4*)(q + 4);
  short8 r = {bfs(a.x), bfs(a.y), bfs(a.z), bfs(a.w),
              bfs(b.x), bfs(b.y), bfs(b.z), bfs(b.w)};
  return r;
}

// ---------------------------------------------------------------- transpose
// x fp32 [B][N][D] -> X bf16 [N][B][D]
__global__ __launch_bounds__(256) void k_transpose(const float* __restrict__ x,
                                                   bf16* __restrict__ X) {
  int tid = blockIdx.x * 256 + threadIdx.x;
  if (tid >= NN * BB * DD) return;
  int d = tid & (DD - 1);
  int rest = tid >> 7;
  int b = rest & (BB - 1);
  int node = rest >> 8;
  X[tid] = (bf16)x[((size_t)b * NN + node) * DD + d];
}

// ---------------------------------------------------------------- node GEMM (plain)
__global__ __launch_bounds__(256) void k_gemm(const bf16* __restrict__ A,
                                              const float* __restrict__ W,
                                              const float* __restrict__ bias,
                                              bf16* __restrict__ out, int nout,
                                              int astride, size_t woff, int wns,
                                              size_t boff, int bns, int relu) {
  int nchunks = nout >> 6;
  int bpn = nchunks << 2;
  int node = blockIdx.x / bpn;
  int t = blockIdx.x - node * bpn;
  int wave = threadIdx.x >> 6;
  int lane = threadIdx.x & 63;
  int tile = t * 4 + wave;
  int nc = tile >> 4;
  int mt = tile & 15;
  int r = lane & 15;
  int quad = lane >> 4;

  const bf16* arow = A + ((size_t)node * BB + mt * 16 + r) * (size_t)astride + quad * 8;
  const float* wrow = W + woff + (size_t)node * (size_t)wns + (size_t)(nc * 64 + r) * DD + quad * 8;

  floatx4 acc[4];
  floatx4 z = {0.f, 0.f, 0.f, 0.f};
#pragma unroll
  for (int s = 0; s < 4; s++) acc[s] = z;

#pragma unroll
  for (int k0 = 0; k0 < DD; k0 += 32) {
    short8 af = *(const short8*)(arow + k0);
#pragma unroll
    for (int s = 0; s < 4; s++) {
      short8 bq = ldw8(wrow + (size_t)s * 16 * DD + k0);
      acc[s] = __builtin_amdgcn_mfma_f32_16x16x32_bf16(af, bq, acc[s], 0, 0, 0);
    }
  }

  const float* bp = bias + boff + (size_t)node * (size_t)bns + nc * 64;
#pragma unroll
  for (int s = 0; s < 4; s++) {
    float bv = bp[s * 16 + r];
#pragma unroll
    for (int i = 0; i < 4; i++) {
      float v = acc[s][i] + bv;
      if (relu) v = v > 0.f ? v : 0.f;
      int row = mt * 16 + quad * 4 + i;
      out[((size_t)node * BB + row) * (size_t)nout + nc * 64 + s * 16 + r] = (bf16)v;
    }
  }
}

// ---------------------------------------------------------------- GEMM + residual + LN
__global__ __launch_bounds__(256) void k_gemm_ln(const bf16* __restrict__ A, int astride,
                                                 const float* __restrict__ W,
                                                 const float* __restrict__ bias,
                                                 bf16* __restrict__ X,
                                                 const float* __restrict__ g,
                                                 const float* __restrict__ be,
                                                 size_t woff, int wns, size_t boff,
                                                 int bns, int gstride) {
  __shared__ float Sm[32 * 128];  // 16 KB
  int node = blockIdx.x >> 3;
  int bt = blockIdx.x & 7;
  int w = threadIdx.x >> 6;
  int lane = threadIdx.x & 63;
  int r = lane & 15, quad = lane >> 4;
  int rt = w & 1;
  int nc = w >> 1;

  const bf16* arow = A + ((size_t)node * BB + bt * 32 + rt * 16 + r) * (size_t)astride + quad * 8;
  const float* wrow = W + woff + (size_t)node * (size_t)wns + (size_t)(nc * 64 + r) * DD + quad * 8;

  floatx4 acc[4];
  floatx4 z = {0.f, 0.f, 0.f, 0.f};
#pragma unroll
  for (int s = 0; s < 4; s++) acc[s] = z;
#pragma unroll
  for (int k0 = 0; k0 < DD; k0 += 32) {
    short8 af = *(const short8*)(arow + k0);
#pragma unroll
    for (int s = 0; s < 4; s++) {
      short8 bq = ldw8(wrow + (size_t)s * 16 * DD + k0);
      acc[s] = __builtin_amdgcn_mfma_f32_16x16x32_bf16(af, bq, acc[s], 0, 0, 0);
    }
  }
  const float* bp = bias + boff + (size_t)node * (size_t)bns + nc * 64;
#pragma unroll
  for (int s = 0; s < 4; s++) {
    float bv = bp[s * 16 + r];
#pragma unroll
    for (int i = 0; i < 4; i++)
      Sm[(rt * 16 + quad * 4 + i) * 128 + nc * 64 + s * 16 + r] = acc[s][i] + bv;
  }
  __syncthreads();

  int row = threadIdx.x >> 3;  // 0..31
  int sub = threadIdx.x & 7;   // col group of 16
  size_t xbase = ((size_t)node * BB + bt * 32 + row) * DD + sub * 16;
  float v[16];
  float sum = 0.f;
#pragma unroll
  for (int j = 0; j < 16; j++) {
    v[j] = Sm[row * 128 + sub * 16 + j] + (float)X[xbase + j];
    sum += v[j];
  }
  sum += __shfl_xor(sum, 1);
  sum += __shfl_xor(sum, 2);
  sum += __shfl_xor(sum, 4);
  float mean = sum * (1.0f / 128.0f);
  float vs = 0.f;
#pragma unroll
  for (int j = 0; j < 16; j++) {
    float c = v[j] - mean;
    vs += c * c;
  }
  vs += __shfl_xor(vs, 1);
  vs += __shfl_xor(vs, 2);
  vs += __shfl_xor(vs, 4);
  float inv = rsqrtf(vs * (1.0f / 128.0f) + 1e-5f);
  const float* gp = g + boff + (size_t)node * gstride + sub * 16;
  const float* bep = be + boff + (size_t)node * gstride + sub * 16;
#pragma unroll
  for (int j = 0; j < 16; j++)
    X[xbase + j] = (bf16)((v[j] - mean) * inv * gp[j] + bep[j]);
}

// ---------------------------------------------------------------- attention (in-place, Q slot)
__global__ __launch_bounds__(256) void k_attn(bf16* __restrict__ QKV) {
  __shared__ float Ks[BB * DH];  // 32 KB
  __shared__ float Vs[BB * DH];  // 32 KB
  int node = blockIdx.x >> 2, h = blockIdx.x & 3;
  int tid = threadIdx.x;
  bf16* base = QKV + (size_t)node * BB * 384;

  for (int i = tid; i < BB * DH; i += 256) {
    int row = i >> 5, d = i & 31;
    Ks[i] = (float)base[row * 384 + 128 + h * 32 + d];
    Vs[i] = (float)base[row * 384 + 256 + h * 32 + d];
  }
  float q[DH];
#pragma unroll
  for (int d = 0; d < DH; d++) q[d] = (float)base[tid * 384 + h * 32 + d];
  __syncthreads();

  float l = 0.f, o[DH];
#pragma unroll
  for (int d = 0; d < DH; d++) o[d] = 0.f;
  const float scale = 0.17677669529663689f;  // 1/sqrt(32)

  for (int kk = 0; kk < BB; kk++) {
    const float* kr = &Ks[kk * DH];
    float s = 0.f;
#pragma unroll
    for (int d = 0; d < DH; d++) s += q[d] * kr[d];
    float p = __expf(s * scale);
    l += p;
    const float* vr = &Vs[kk * DH];
#pragma unroll
    for (int d = 0; d < DH; d++) o[d] += p * vr[d];
  }
  float inv = 1.0f / l;
  bf16* qout = base + tid * 384 + h * 32;
#pragma unroll
  for (int d = 0; d < DH; d++) qout[d] = (bf16)(o[d] * inv);
}

// ---------------------------------------------------------------- GAT row scalars
// wave per flat row j=b*N+n: h = feat @ gat_W.T (in lanes), then 4 wave-reduced dots:
// a_s = h.att_src, a_d = h.att_dst, hw0 = h.predW[0], hw1 = h.predW[1]
__global__ __launch_bounds__(256) void k_gath(const bf16* __restrict__ FEAT,
                                              const float* __restrict__ gatW,
                                              const float* __restrict__ attS,
                                              const float* __restrict__ attD,
                                              const float* __restrict__ predW,
                                              float* __restrict__ AS,
                                              float* __restrict__ ADv,
                                              float* __restrict__ HW0,
                                              float* __restrict__ HW1) {
  __shared__ float Wt[64 * 64];  // Wt[k*64+j] = gat_W[j][k]
  int tid = threadIdx.x;
  for (int i = tid; i < 64 * 64; i += 256) {
    int k = i >> 6, j = i & 63;
    Wt[i] = gatW[j * 64 + k];
  }
  __syncthreads();
  int wave = tid >> 6, lane = tid & 63;
  int row = blockIdx.x * 4 + wave;  // flat j = b*N+n
  float f = (float)FEAT[(size_t)row * 64 + lane];
  float h = 0.f;
#pragma unroll
  for (int k = 0; k < 64; k++) {
    float fk = __shfl(f, k, 64);
    h += fk * Wt[k * 64 + lane];
  }
  float ps = h * attS[lane];
  float pd = h * attD[lane];
  float h0 = h * predW[lane];
  float h1 = h * predW[64 + lane];
#pragma unroll
  for (int off = 32; off; off >>= 1) {
    ps += __shfl_down(ps, off);
    pd += __shfl_down(pd, off);
    h0 += __shfl_down(h0, off);
    h1 += __shfl_down(h1, off);
  }
  if (lane == 0) {
    AS[row] = ps;
    ADv[row] = pd;
    HW0[row] = h0;
    HW1[row] = h1;
  }
}

// ---------------------------------------------------------------- zero
__global__ __launch_bounds__(256) void k_zero(float4* __restrict__ p, int n4) {
  int i = blockIdx.x * 256 + threadIdx.x;
  if (i < n4) p[i] = make_float4(0.f, 0.f, 0.f, 0.f);
}

// ---------------------------------------------------------------- edges -> 3 scalar accumulators
// OUT[b,d,c] = (sum_e w_e * HW_c[b,src]) / (sum_e w_e) + const_c  -- exact linear collapse
__global__ __launch_bounds__(256) void k_edge(const int* __restrict__ EI,
                                              const float* __restrict__ AS,
                                              const float* __restrict__ ADv,
                                              const float* __restrict__ HW0,
                                              const float* __restrict__ HW1,
                                              float* __restrict__ NUM0,
                                              float* __restrict__ NUM1,
                                              float* __restrict__ DEN) {
  int tid = blockIdx.x * 256 + threadIdx.x;
  if (tid >= BB * (NE + NN)) return;
  int b = tid / (NE + NN);
  int e = tid - b * (NE + NN);
  int s, d;
  if (e < NE) {
    s = EI[e];
    d = EI[NE + e];
  } else {
    s = d = e - NE;  // self loop
  }
  int js = b * NN + s, jd = b * NN + d;
  float ev = AS[js] + ADv[jd];
  float lr = ev > 0.f ? ev : 0.2f * ev;
  float w = __expf(lr);
  atomicAdd(&NUM0[jd], w * HW0[js]);
  atomicAdd(&NUM1[jd], w * HW1[js]);
  atomicAdd(&DEN[jd], w);
}

// ---------------------------------------------------------------- finalize
__global__ __launch_bounds__(256) void k_fin(const float* __restrict__ NUM0,
                                             const float* __restrict__ NUM1,
                                             const float* __restrict__ DEN,
                                             const float* __restrict__ gatB,
                                             const float* __restrict__ predW,
                                             const float* __restrict__ predB,
                                             float* __restrict__ OUT) {
  int tid = blockIdx.x * 256 + threadIdx.x;
  if (tid >= BB * NN) return;
  float c0 = predB[0], c1 = predB[1];
#pragma unroll
  for (int f = 0; f < 64; f++) {
    float gb = gatB[f];
    c0 += gb * predW[f];
    c1 += gb * predW[64 + f];
  }
  float inv = 1.0f / (DEN[tid] + 1e-16f);
  OUT[2 * tid] = NUM0[tid] * inv + c0;
  OUT[2 * tid + 1] = NUM1[tid] * inv + c1;
}

// ================================================================ launch
extern "C" void kernel_launch(void* const* d_in, const int* in_sizes, int n_in,
                              void* d_out, int out_size, void* d_ws, size_t ws_size,
                              hipStream_t stream) {
  const float* x = (const float*)d_in[0];
  const int* ei = (const int*)d_in[1];
  const float* Wqkv = (const float*)d_in[2];
  const float* bqkv = (const float*)d_in[3];
  const float* Wo = (const float*)d_in[4];
  const float* bo = (const float*)d_in[5];
  const float* g1 = (const float*)d_in[6];
  const float* be1 = (const float*)d_in[7];
  const float* fW1 = (const float*)d_in[8];
  const float* fb1 = (const float*)d_in[9];
  const float* fW2 = (const float*)d_in[10];
  const float* fb2 = (const float*)d_in[11];
  const float* g2 = (const float*)d_in[12];
  const float* be2 = (const float*)d_in[13];
  const float* fcW = (const float*)d_in[14];
  const float* fcb = (const float*)d_in[15];
  const float* gatW = (const float*)d_in[16];
  const float* attS = (const float*)d_in[17];
  const float* attD = (const float*)d_in[18];
  const float* gatB = (const float*)d_in[19];
  const float* predW = (const float*)d_in[20];
  const float* predB = (const float*)d_in[21];

  const size_t NEED = 52428800;
  if (ws_size < NEED) return;  // signature: absmax == max|ref|

  char* ws = (char*)d_ws;
  bf16* X = (bf16*)(ws);                  // [N][B][128]   0 .. 13,107,200
  bf16* QKV = (bf16*)(ws + 13107200);     // [N][B][384]  .. 52,428,800 (reused as H1)
  // GAT-phase overlays (QKV dead; X live until FEAT gemm done):
  bf16* FEAT = (bf16*)(ws + 40960000);    // [N*B][64]    .. 47,513,600
  float* AS = (float*)(ws + 47513600);    // [51200]
  float* ADv = (float*)(ws + 47718400);   // [51200]
  float* HW0 = (float*)(ws + 47923200);   // [51200]
  float* HW1 = (float*)(ws + 48128000);   // [51200]
  float* NUM0 = (float*)(ws + 48332800);  // [51200]
  float* NUM1 = (float*)(ws + 48537600);  // [51200]
  float* DEN = (float*)(ws + 48742400);   // [51200] .. 48,947,200

  k_transpose<<<25600, 256, 0, stream>>>(x, X);

  for (int l = 0; l < LL; l++) {
    size_t w3o = (size_t)l * 384 * DD, b3o = (size_t)l * 384;
    size_t wso = (size_t)l * DD * DD, bso = (size_t)l * DD;
    // QKV = X @ Wqkv^T + bqkv -> bf16 [N][256][384]
    k_gemm<<<24 * NN, 256, 0, stream>>>(X, Wqkv, bqkv, QKV, 384, DD,
                                        w3o, LL * 384 * DD, b3o, LL * 384, 0);
    // attention in-place into Q slot
    k_attn<<<NN * 4, 256, 0, stream>>>(QKV);
    // X = LN(X + ATT @ Wo^T + bo; g1, be1)
    k_gemm_ln<<<8 * NN, 256, 0, stream>>>(QKV, 384, Wo, bo, X, g1, be1,
                                          wso, LL * DD * DD, bso, LL * DD, LL * DD);
    // H1 = relu(X @ fW1^T + fb1) -> bf16 (into QKV region)
    k_gemm<<<8 * NN, 256, 0, stream>>>(X, fW1, fb1, QKV, 128, DD,
                                       wso, LL * DD * DD, bso, LL * DD, 1);
    // X = LN(X + H1 @ fW2^T + fb2; g2, be2)
    k_gemm_ln<<<8 * NN, 256, 0, stream>>>(QKV, 128, fW2, fb2, X, g2, be2,
                                          wso, LL * DD * DD, bso, LL * DD, LL * DD);
  }

  // FEAT = X @ fc_W^T + fc_b (shared) -> bf16 [N*B][64]
  k_gemm<<<4 * NN, 256, 0, stream>>>(X, fcW, fcb, FEAT, 64, DD, 0, 0, 0, 0, 0);
  // per-row scalars: a_s, a_d, h.predW0, h.predW1
  k_gath<<<12800, 256, 0, stream>>>(FEAT, gatW, attS, attD, predW, AS, ADv, HW0, HW1);
  // zero NUM0/NUM1/DEN (contiguous 3*51200 floats)
  k_zero<<<150, 256, 0, stream>>>((float4*)NUM0, 38400);
  // edge scatter: 3 atomics per (b, edge)
  k_edge<<<1800, 256, 0, stream>>>(ei, AS, ADv, HW0, HW1, NUM0, NUM1, DEN);
  // OUT[b][n][c] = NUM_c/DEN + (gatB.predW_c + predB_c)
  k_fin<<<200, 256, 0, stream>>>(NUM0, NUM1, DEN, gatB, predW, predB, (float*)d_out);
}

// Round 6
// 760.443 us; speedup vs baseline: 1.5434x; 1.3047x over previous
//
#include <hip/hip_runtime.h>
#include <hip/hip_bf16.h>

#define NN 200   // nodes
#define BB 256   // batch == attention sequence length
#define DD 128   // d_model == seq
#define DH 32    // head dim
#define NE 1600  // edges
#define LL 2     // layers

typedef short short8 __attribute__((ext_vector_type(8)));
typedef short short4a __attribute__((ext_vector_type(4)));
typedef float floatx4 __attribute__((ext_vector_type(4)));
using bf16 = __hip_bfloat16;

// Inputs fp32 (proven R1-R3); output fp32.

__device__ __forceinline__ short bfs(float x) {
  bf16 h = __float2bfloat16(x);
  return *(short*)&h;
}
__device__ __forceinline__ short8 ldw8(const float* q) {
  float4 a = *(const float4*)q;
  float4 b = *(const float4*)(q + 4);
  short8 r = {bfs(a.x), bfs(a.y), bfs(a.z), bfs(a.w),
              bfs(b.x), bfs(b.y), bfs(b.z), bfs(b.w)};
  return r;
}

// ---------------------------------------------------------------- transpose
__global__ __launch_bounds__(256) void k_transpose(const float* __restrict__ x,
                                                   bf16* __restrict__ X) {
  int tid = blockIdx.x * 256 + threadIdx.x;
  if (tid >= NN * BB * DD) return;
  int d = tid & (DD - 1);
  int rest = tid >> 7;
  int b = rest & (BB - 1);
  int node = rest >> 8;
  X[tid] = (bf16)x[((size_t)b * NN + node) * DD + d];
}

// ---------------------------------------------------------------- node GEMM (plain)
__global__ __launch_bounds__(256) void k_gemm(const bf16* __restrict__ A,
                                              const float* __restrict__ W,
                                              const float* __restrict__ bias,
                                              bf16* __restrict__ out, int nout,
                                              int astride, size_t woff, int wns,
                                              size_t boff, int bns, int relu) {
  int nchunks = nout >> 6;
  int bpn = nchunks << 2;
  int node = blockIdx.x / bpn;
  int t = blockIdx.x - node * bpn;
  int wave = threadIdx.x >> 6;
  int lane = threadIdx.x & 63;
  int tile = t * 4 + wave;
  int nc = tile >> 4;
  int mt = tile & 15;
  int r = lane & 15;
  int quad = lane >> 4;

  const bf16* arow = A + ((size_t)node * BB + mt * 16 + r) * (size_t)astride + quad * 8;
  const float* wrow = W + woff + (size_t)node * (size_t)wns + (size_t)(nc * 64 + r) * DD + quad * 8;

  floatx4 acc[4];
  floatx4 z = {0.f, 0.f, 0.f, 0.f};
#pragma unroll
  for (int s = 0; s < 4; s++) acc[s] = z;

#pragma unroll
  for (int k0 = 0; k0 < DD; k0 += 32) {
    short8 af = *(const short8*)(arow + k0);
#pragma unroll
    for (int s = 0; s < 4; s++) {
      short8 bq = ldw8(wrow + (size_t)s * 16 * DD + k0);
      acc[s] = __builtin_amdgcn_mfma_f32_16x16x32_bf16(af, bq, acc[s], 0, 0, 0);
    }
  }

  const float* bp = bias + boff + (size_t)node * (size_t)bns + nc * 64;
#pragma unroll
  for (int s = 0; s < 4; s++) {
    float bv = bp[s * 16 + r];
#pragma unroll
    for (int i = 0; i < 4; i++) {
      float v = acc[s][i] + bv;
      if (relu) v = v > 0.f ? v : 0.f;
      int row = mt * 16 + quad * 4 + i;
      out[((size_t)node * BB + row) * (size_t)nout + nc * 64 + s * 16 + r] = (bf16)v;
    }
  }
}

// ---------------------------------------------------------------- GEMM + residual + LN
__global__ __launch_bounds__(256) void k_gemm_ln(const bf16* __restrict__ A, int astride,
                                                 const float* __restrict__ W,
                                                 const float* __restrict__ bias,
                                                 bf16* __restrict__ X,
                                                 const float* __restrict__ g,
                                                 const float* __restrict__ be,
                                                 size_t woff, int wns, size_t boff,
                                                 int bns, int gstride) {
  __shared__ float Sm[32 * 128];  // 16 KB
  int node = blockIdx.x >> 3;
  int bt = blockIdx.x & 7;
  int w = threadIdx.x >> 6;
  int lane = threadIdx.x & 63;
  int r = lane & 15, quad = lane >> 4;
  int rt = w & 1;
  int nc = w >> 1;

  const bf16* arow = A + ((size_t)node * BB + bt * 32 + rt * 16 + r) * (size_t)astride + quad * 8;
  const float* wrow = W + woff + (size_t)node * (size_t)wns + (size_t)(nc * 64 + r) * DD + quad * 8;

  floatx4 acc[4];
  floatx4 z = {0.f, 0.f, 0.f, 0.f};
#pragma unroll
  for (int s = 0; s < 4; s++) acc[s] = z;
#pragma unroll
  for (int k0 = 0; k0 < DD; k0 += 32) {
    short8 af = *(const short8*)(arow + k0);
#pragma unroll
    for (int s = 0; s < 4; s++) {
      short8 bq = ldw8(wrow + (size_t)s * 16 * DD + k0);
      acc[s] = __builtin_amdgcn_mfma_f32_16x16x32_bf16(af, bq, acc[s], 0, 0, 0);
    }
  }
  const float* bp = bias + boff + (size_t)node * (size_t)bns + nc * 64;
#pragma unroll
  for (int s = 0; s < 4; s++) {
    float bv = bp[s * 16 + r];
#pragma unroll
    for (int i = 0; i < 4; i++)
      Sm[(rt * 16 + quad * 4 + i) * 128 + nc * 64 + s * 16 + r] = acc[s][i] + bv;
  }
  __syncthreads();

  int row = threadIdx.x >> 3;  // 0..31
  int sub = threadIdx.x & 7;   // col group of 16
  size_t xbase = ((size_t)node * BB + bt * 32 + row) * DD + sub * 16;
  float v[16];
  float sum = 0.f;
#pragma unroll
  for (int j = 0; j < 16; j++) {
    v[j] = Sm[row * 128 + sub * 16 + j] + (float)X[xbase + j];
    sum += v[j];
  }
  sum += __shfl_xor(sum, 1);
  sum += __shfl_xor(sum, 2);
  sum += __shfl_xor(sum, 4);
  float mean = sum * (1.0f / 128.0f);
  float vs = 0.f;
#pragma unroll
  for (int j = 0; j < 16; j++) {
    float c = v[j] - mean;
    vs += c * c;
  }
  vs += __shfl_xor(vs, 1);
  vs += __shfl_xor(vs, 2);
  vs += __shfl_xor(vs, 4);
  float inv = rsqrtf(vs * (1.0f / 128.0f) + 1e-5f);
  const float* gp = g + boff + (size_t)node * gstride + sub * 16;
  const float* bep = be + boff + (size_t)node * gstride + sub * 16;
#pragma unroll
  for (int j = 0; j < 16; j++)
    X[xbase + j] = (bf16)((v[j] - mean) * inv * gp[j] + bep[j]);
}

// ---------------------------------------------------------------- MFMA attention (in-place, Q slot)
// block = (node, head); 4 waves x 64 queries. S^T = K.Q^T via mfma (A=K rows,
// B=Q rows -> S^T C-layout: key on quad axis, query on lane&15). exp -> wave-
// private LDS bounce re-forms P^T as the B-operand; A = V^T (LDS-staged) ->
// O^T accumulates in C-layout. Denominator = 2 shfl_xor (quads hold disjoint
// keys). Epilogue transposes O via the same scratch for coalesced b128 stores.
__global__ __launch_bounds__(256) void k_attn(bf16* __restrict__ QKV) {
  __shared__ short VT[32 * 264];  // V^T [d][key], padded row stride 264 (16.9 KB)
  __shared__ short Pw[4 * 2560];  // per-wave P / O scratch, [16 rows][40] per qt (10.2 KB)
  int node = blockIdx.x >> 2, h = blockIdx.x & 3;
  int tid = threadIdx.x;
  int wave = tid >> 6, lane = tid & 63, quad = lane >> 4, l15 = lane & 15;
  short* sbase = (short*)(QKV + (size_t)node * BB * 384);

  // stage V^T: VT[d][key] = V[key][d]
  for (int i = tid; i < 4096; i += 256) {
    int key = i >> 4, dp = (i & 15) << 1;
    int two = *(const int*)(sbase + (size_t)key * 384 + 256 + h * 32 + dp);
    VT[dp * 264 + key] = (short)(two & 0xffff);
    VT[(dp + 1) * 264 + key] = (short)(((unsigned)two) >> 16);
  }

  // Q B-frags for this wave's 64 queries (read before any Q-slot write)
  int q0 = wave * 64;
  short8 qf[4];
#pragma unroll
  for (int qt = 0; qt < 4; qt++)
    qf[qt] = *(const short8*)(sbase + (size_t)(q0 + qt * 16 + l15) * 384 + h * 32 + quad * 8);

  __syncthreads();  // VT ready

  floatx4 zz = {0.f, 0.f, 0.f, 0.f};
  floatx4 acc[2][4];
#pragma unroll
  for (int dt = 0; dt < 2; dt++)
#pragma unroll
    for (int qt = 0; qt < 4; qt++) acc[dt][qt] = zz;
  float lp[4] = {0.f, 0.f, 0.f, 0.f};
  const float scale = 0.17677669529663689f;  // 1/sqrt(32)
  short* mypw = &Pw[wave * 2560];

  for (int g = 0; g < 8; g++) {
#pragma unroll
    for (int sub = 0; sub < 2; sub++) {
      int kt = g * 2 + sub;
      short8 kf = *(const short8*)(sbase + (size_t)(kt * 16 + l15) * 384 + 128 + h * 32 + quad * 8);
#pragma unroll
      for (int qt = 0; qt < 4; qt++) {
        floatx4 st = __builtin_amdgcn_mfma_f32_16x16x32_bf16(kf, qf[qt], zz, 0, 0, 0);
        float e0 = __expf(st[0] * scale);
        float e1 = __expf(st[1] * scale);
        float e2 = __expf(st[2] * scale);
        float e3 = __expf(st[3] * scale);
        lp[qt] += (e0 + e1) + (e2 + e3);
        short4a p = {bfs(e0), bfs(e1), bfs(e2), bfs(e3)};
        // P^T scratch: [query=l15][key = sub*16 + quad*4 .. +3], row stride 40
        *(short4a*)(mypw + qt * 640 + l15 * 40 + sub * 16 + quad * 4) = p;
      }
    }
    // V^T A-frags: A[m=d=l15][k=key=g*32+quad*8+j]
    short8 vf0 = *(const short8*)(&VT[l15 * 264 + g * 32 + quad * 8]);
    short8 vf1 = *(const short8*)(&VT[(16 + l15) * 264 + g * 32 + quad * 8]);
#pragma unroll
    for (int qt = 0; qt < 4; qt++) {
      short8 pf = *(const short8*)(mypw + qt * 640 + l15 * 40 + quad * 8);
      acc[0][qt] = __builtin_amdgcn_mfma_f32_16x16x32_bf16(vf0, pf, acc[0][qt], 0, 0, 0);
      acc[1][qt] = __builtin_amdgcn_mfma_f32_16x16x32_bf16(vf1, pf, acc[1][qt], 0, 0, 0);
    }
  }

  // denominators: quads hold disjoint key subsets for the same query (lane&15)
  float inv[4];
#pragma unroll
  for (int qt = 0; qt < 4; qt++) {
    float lq = lp[qt];
    lq += __shfl_xor(lq, 16);
    lq += __shfl_xor(lq, 32);
    inv[qt] = 1.0f / lq;
  }

  // O^T (C-layout) -> wave-private scratch as O[query][d] bf16 (row stride 40)
#pragma unroll
  for (int qt = 0; qt < 4; qt++)
#pragma unroll
    for (int dt = 0; dt < 2; dt++)
#pragma unroll
      for (int i = 0; i < 4; i++)
        mypw[(qt * 16 + l15) * 40 + dt * 16 + quad * 4 + i] = bfs(acc[dt][qt][i] * inv[qt]);

  // coalesced in-place store to the Q slot (wave-private rows; K/V cols disjoint)
#pragma unroll
  for (int r = 0; r < 4; r++) {
    int chunk = r * 64 + lane;
    int query = chunk >> 2, d8 = (chunk & 3) * 8;
    short8 o = *(const short8*)(mypw + query * 40 + d8);
    *(short8*)(sbase + (size_t)(q0 + query) * 384 + h * 32 + d8) = o;
  }
}

// ---------------------------------------------------------------- GAT row scalars
__global__ __launch_bounds__(256) void k_gath(const bf16* __restrict__ FEAT,
                                              const float* __restrict__ gatW,
                                              const float* __restrict__ attS,
                                              const float* __restrict__ attD,
                                              const float* __restrict__ predW,
                                              float* __restrict__ AS,
                                              float* __restrict__ ADv,
                                              float* __restrict__ HW0,
                                              float* __restrict__ HW1) {
  __shared__ float Wt[64 * 64];  // Wt[k*64+j] = gat_W[j][k]
  int tid = threadIdx.x;
  for (int i = tid; i < 64 * 64; i += 256) {
    int k = i >> 6, j = i & 63;
    Wt[i] = gatW[j * 64 + k];
  }
  __syncthreads();
  int wave = tid >> 6, lane = tid & 63;
  int row = blockIdx.x * 4 + wave;
  float f = (float)FEAT[(size_t)row * 64 + lane];
  float h = 0.f;
#pragma unroll
  for (int k = 0; k < 64; k++) {
    float fk = __shfl(f, k, 64);
    h += fk * Wt[k * 64 + lane];
  }
  float ps = h * attS[lane];
  float pd = h * attD[lane];
  float h0 = h * predW[lane];
  float h1 = h * predW[64 + lane];
#pragma unroll
  for (int off = 32; off; off >>= 1) {
    ps += __shfl_down(ps, off);
    pd += __shfl_down(pd, off);
    h0 += __shfl_down(h0, off);
    h1 += __shfl_down(h1, off);
  }
  if (lane == 0) {
    AS[row] = ps;
    ADv[row] = pd;
    HW0[row] = h0;
    HW1[row] = h1;
  }
}

// ---------------------------------------------------------------- zero
__global__ __launch_bounds__(256) void k_zero(float4* __restrict__ p, int n4) {
  int i = blockIdx.x * 256 + threadIdx.x;
  if (i < n4) p[i] = make_float4(0.f, 0.f, 0.f, 0.f);
}

// ---------------------------------------------------------------- edges -> 3 scalar accumulators
__global__ __launch_bounds__(256) void k_edge(const int* __restrict__ EI,
                                              const float* __restrict__ AS,
                                              const float* __restrict__ ADv,
                                              const float* __restrict__ HW0,
                                              const float* __restrict__ HW1,
                                              float* __restrict__ NUM0,
                                              float* __restrict__ NUM1,
                                              float* __restrict__ DEN) {
  int tid = blockIdx.x * 256 + threadIdx.x;
  if (tid >= BB * (NE + NN)) return;
  int b = tid / (NE + NN);
  int e = tid - b * (NE + NN);
  int s, d;
  if (e < NE) {
    s = EI[e];
    d = EI[NE + e];
  } else {
    s = d = e - NE;  // self loop
  }
  int js = b * NN + s, jd = b * NN + d;
  float ev = AS[js] + ADv[jd];
  float lr = ev > 0.f ? ev : 0.2f * ev;
  float w = __expf(lr);
  atomicAdd(&NUM0[jd], w * HW0[js]);
  atomicAdd(&NUM1[jd], w * HW1[js]);
  atomicAdd(&DEN[jd], w);
}

// ---------------------------------------------------------------- finalize
__global__ __launch_bounds__(256) void k_fin(const float* __restrict__ NUM0,
                                             const float* __restrict__ NUM1,
                                             const float* __restrict__ DEN,
                                             const float* __restrict__ gatB,
                                             const float* __restrict__ predW,
                                             const float* __restrict__ predB,
                                             float* __restrict__ OUT) {
  int tid = blockIdx.x * 256 + threadIdx.x;
  if (tid >= BB * NN) return;
  float c0 = predB[0], c1 = predB[1];
#pragma unroll
  for (int f = 0; f < 64; f++) {
    float gb = gatB[f];
    c0 += gb * predW[f];
    c1 += gb * predW[64 + f];
  }
  float inv = 1.0f / (DEN[tid] + 1e-16f);
  OUT[2 * tid] = NUM0[tid] * inv + c0;
  OUT[2 * tid + 1] = NUM1[tid] * inv + c1;
}

// ================================================================ launch
extern "C" void kernel_launch(void* const* d_in, const int* in_sizes, int n_in,
                              void* d_out, int out_size, void* d_ws, size_t ws_size,
                              hipStream_t stream) {
  const float* x = (const float*)d_in[0];
  const int* ei = (const int*)d_in[1];
  const float* Wqkv = (const float*)d_in[2];
  const float* bqkv = (const float*)d_in[3];
  const float* Wo = (const float*)d_in[4];
  const float* bo = (const float*)d_in[5];
  const float* g1 = (const float*)d_in[6];
  const float* be1 = (const float*)d_in[7];
  const float* fW1 = (const float*)d_in[8];
  const float* fb1 = (const float*)d_in[9];
  const float* fW2 = (const float*)d_in[10];
  const float* fb2 = (const float*)d_in[11];
  const float* g2 = (const float*)d_in[12];
  const float* be2 = (const float*)d_in[13];
  const float* fcW = (const float*)d_in[14];
  const float* fcb = (const float*)d_in[15];
  const float* gatW = (const float*)d_in[16];
  const float* attS = (const float*)d_in[17];
  const float* attD = (const float*)d_in[18];
  const float* gatB = (const float*)d_in[19];
  const float* predW = (const float*)d_in[20];
  const float* predB = (const float*)d_in[21];

  const size_t NEED = 52428800;
  if (ws_size < NEED) return;  // signature: absmax == max|ref|

  char* ws = (char*)d_ws;
  bf16* X = (bf16*)(ws);                  // [N][B][128]   0 .. 13,107,200
  bf16* QKV = (bf16*)(ws + 13107200);     // [N][B][384]  .. 52,428,800 (reused as H1)
  bf16* FEAT = (bf16*)(ws + 40960000);    // [N*B][64]    .. 47,513,600
  float* AS = (float*)(ws + 47513600);    // [51200]
  float* ADv = (float*)(ws + 47718400);   // [51200]
  float* HW0 = (float*)(ws + 47923200);   // [51200]
  float* HW1 = (float*)(ws + 48128000);   // [51200]
  float* NUM0 = (float*)(ws + 48332800);  // [51200]
  float* NUM1 = (float*)(ws + 48537600);  // [51200]
  float* DEN = (float*)(ws + 48742400);   // [51200]

  k_transpose<<<25600, 256, 0, stream>>>(x, X);

  for (int l = 0; l < LL; l++) {
    size_t w3o = (size_t)l * 384 * DD, b3o = (size_t)l * 384;
    size_t wso = (size_t)l * DD * DD, bso = (size_t)l * DD;
    k_gemm<<<24 * NN, 256, 0, stream>>>(X, Wqkv, bqkv, QKV, 384, DD,
                                        w3o, LL * 384 * DD, b3o, LL * 384, 0);
    k_attn<<<NN * 4, 256, 0, stream>>>(QKV);
    k_gemm_ln<<<8 * NN, 256, 0, stream>>>(QKV, 384, Wo, bo, X, g1, be1,
                                          wso, LL * DD * DD, bso, LL * DD, LL * DD);
    k_gemm<<<8 * NN, 256, 0, stream>>>(X, fW1, fb1, QKV, 128, DD,
                                       wso, LL * DD * DD, bso, LL * DD, 1);
    k_gemm_ln<<<8 * NN, 256, 0, stream>>>(QKV, 128, fW2, fb2, X, g2, be2,
                                          wso, LL * DD * DD, bso, LL * DD, LL * DD);
  }

  k_gemm<<<4 * NN, 256, 0, stream>>>(X, fcW, fcb, FEAT, 64, DD, 0, 0, 0, 0, 0);
  k_gath<<<12800, 256, 0, stream>>>(FEAT, gatW, attS, attD, predW, AS, ADv, HW0, HW1);
  k_zero<<<150, 256, 0, stream>>>((float4*)NUM0, 38400);
  k_edge<<<1800, 256, 0, stream>>>(ei, AS, ADv, HW0, HW1, NUM0, NUM1, DEN);
  k_fin<<<200, 256, 0, stream>>>(NUM0, NUM1, DEN, gatB, predW, predB, (float*)d_out);
}